// Round 1
// baseline (177.612 us; speedup 1.0000x reference)
//
#include <hip/hip_runtime.h>

// KGCN forward, MI355X. One wave (64 lanes) per batch element, lane = dim.
// B=16384, D=64, N_NEIGHBOR=8, N_ITER=2. All fp32 (no fp32 MFMA on CDNA4 ->
// vector ALU matvecs). 4 waves/block -> ~19.7KB LDS/block -> 8 blocks/CU.

namespace {

constexpr int kDim      = 64;
constexpr int kNN       = 8;
constexpr int kNumEnt   = 100000;
constexpr int kItemInKG = 20000;
constexpr int kElems    = 4;   // batch elements (waves) per block

__device__ __forceinline__ float fast_sigmoid(float x) {
  return 1.0f / (1.0f + __expf(-x));
}
__device__ __forceinline__ float fast_tanh(float x) {
  return 2.0f / (1.0f + __expf(-2.0f * x)) - 1.0f;
}

__global__ void __launch_bounds__(kElems * 64)
kgcn_kernel(const int* __restrict__ u, const int* __restrict__ v,
            const float* __restrict__ usr_emb, const float* __restrict__ item_emb,
            const float* __restrict__ ent_emb, const float* __restrict__ rel_emb,
            const float* __restrict__ W, const float* __restrict__ bias,
            const int* __restrict__ adj_ent, const int* __restrict__ adj_rel,
            float* __restrict__ out)
{
  const int wv = threadIdx.x >> 6;   // wave within block = element slot
  const int ln = threadIdx.x & 63;   // lane = embedding dim
  const int b  = blockIdx.x * kElems + wv;  // BATCH=16384 divisible by 4

  __shared__ int   s_e1[kElems][kNN];
  __shared__ int   s_r1[kElems][kNN];
  __shared__ int   s_e2[kElems][kDim];
  __shared__ int   s_r2[kElems][kDim];
  __shared__ __align__(16) float s_pre1[kElems][kNN][kDim]; // hop-1 (sv+agg)
  __shared__ __align__(16) float s_h1[kElems][kNN][kDim];   // hop-1 activations
  __shared__ __align__(16) float s_pre0[kElems][kDim];      // hop-0 staging

  const int   uid = u[b];
  const int   vid = v[b];
  const float ue  = usr_emb[uid * kDim + ln];
  const float ev0 = item_emb[vid * kDim + ln];
  // items outside the KG map to the padding entity for neighbor lookup only
  const int   e0  = (vid >= kItemInKG) ? kNumEnt : vid;

  if (ln < kNN) {
    s_e1[wv][ln] = adj_ent[e0 * kNN + ln];
    s_r1[wv][ln] = adj_rel[e0 * kNN + ln];
  }
  __syncthreads();

  // hop-2 adjacency: lane j gets neighbor (j&7) of parent ents1[j>>3]
  {
    const int parent = s_e1[wv][ln >> 3];
    s_e2[wv][ln] = adj_ent[parent * kNN + (ln & 7)];
    s_r2[wv][ln] = adj_rel[parent * kNN + (ln & 7)];
  }

  // hop-1 entity embeddings: only column `ln` of each row is ever needed by
  // this lane -> keep in registers, no LDS.
  float ev1r[kNN];
  #pragma unroll
  for (int m = 0; m < kNN; ++m)
    ev1r[m] = ent_emb[s_e1[wv][m] * kDim + ln];

  // hop-0 attention weights w0[8]: scores = ue . rel_emb[rels1[n]].
  // NOTE: iter-1 hop-0 uses the SAME ue and rv[0] -> weights identical, reuse.
  float w0[kNN];
  {
    float p[kNN];
    #pragma unroll
    for (int n = 0; n < kNN; ++n)
      p[n] = ue * rel_emb[s_r1[wv][n] * kDim + ln];
    #pragma unroll
    for (int off = 32; off > 0; off >>= 1) {
      #pragma unroll
      for (int n = 0; n < kNN; ++n)
        p[n] += __shfl_xor(p[n], off, 64);
    }
    float mx = p[0];
    #pragma unroll
    for (int n = 1; n < kNN; ++n) mx = fmaxf(mx, p[n]);
    float sum = 0.f;
    #pragma unroll
    for (int n = 0; n < kNN; ++n) { w0[n] = __expf(p[n] - mx); sum += w0[n]; }
    const float inv = 1.f / sum;
    #pragma unroll
    for (int n = 0; n < kNN; ++n) w0[n] *= inv;
  }

  // iter-0 hop-0 pre-activation: item_emb[v] + sum_n w0[n]*ent_emb[ents1[n]]
  {
    float agg = 0.f;
    #pragma unroll
    for (int n = 0; n < kNN; ++n) agg = fmaf(w0[n], ev1r[n], agg);
    s_pre0[wv][ln] = ev0 + agg;
  }
  __syncthreads();  // s_e2/s_r2 now visible to all lanes of the wave

  // iter-0 hop-1: for each of the 8 hop-1 entities, attention over its 8
  // hop-2 neighbors; write pre-activation vectors to LDS.
  #pragma unroll 1
  for (int m = 0; m < kNN; ++m) {
    float p[kNN];
    #pragma unroll
    for (int n = 0; n < kNN; ++n)
      p[n] = ue * rel_emb[s_r2[wv][m * kNN + n] * kDim + ln];
    #pragma unroll
    for (int off = 32; off > 0; off >>= 1) {
      #pragma unroll
      for (int n = 0; n < kNN; ++n)
        p[n] += __shfl_xor(p[n], off, 64);
    }
    float mx = p[0];
    #pragma unroll
    for (int n = 1; n < kNN; ++n) mx = fmaxf(mx, p[n]);
    float sum = 0.f;
    #pragma unroll
    for (int n = 0; n < kNN; ++n) { p[n] = __expf(p[n] - mx); sum += p[n]; }
    const float inv = 1.f / sum;  // softmax is linear in agg: scale once
    float agg = 0.f;
    #pragma unroll
    for (int n = 0; n < kNN; ++n)
      agg = fmaf(p[n], ent_emb[s_e2[wv][m * kNN + n] * kDim + ln], agg);
    s_pre1[wv][m][ln] = fmaf(agg, inv, ev1r[m]);
  }
  __syncthreads();  // s_pre0 / s_pre1 complete

  // Matvecs: out[d] = act( sum_k pre[k] * W[d,k] + b[d] ).
  // Lane d streams its W row (float4, L1-hot 16KB) against broadcast LDS reads.
  const float bln = bias[ln];
  const float* __restrict__ wrow = W + ln * kDim;

  float h0a;
  {
    float acc = 0.f;
    #pragma unroll
    for (int k = 0; k < kDim; k += 4) {
      const float4 wk = *reinterpret_cast<const float4*>(wrow + k);
      const float4 pk = *reinterpret_cast<const float4*>(&s_pre0[wv][k]);
      acc = fmaf(wk.x, pk.x, acc);
      acc = fmaf(wk.y, pk.y, acc);
      acc = fmaf(wk.z, pk.z, acc);
      acc = fmaf(wk.w, pk.w, acc);
    }
    h0a = fast_sigmoid(acc + bln);  // iter 0 -> sigmoid
  }

  #pragma unroll 1
  for (int m = 0; m < kNN; ++m) {
    float acc = 0.f;
    #pragma unroll
    for (int k = 0; k < kDim; k += 4) {
      const float4 wk = *reinterpret_cast<const float4*>(wrow + k);
      const float4 pk = *reinterpret_cast<const float4*>(&s_pre1[wv][m][k]);
      acc = fmaf(wk.x, pk.x, acc);
      acc = fmaf(wk.y, pk.y, acc);
      acc = fmaf(wk.z, pk.z, acc);
      acc = fmaf(wk.w, pk.w, acc);
    }
    s_h1[wv][m][ln] = fast_sigmoid(acc + bln);
  }
  __syncthreads();  // s_h1 complete; s_pre0 consumers done -> safe to overwrite

  // iter-1 hop-0: reuse w0; neighbors are the hop-1 activations.
  {
    float agg = 0.f;
    #pragma unroll
    for (int n = 0; n < kNN; ++n) agg = fmaf(w0[n], s_h1[wv][n][ln], agg);
    s_pre0[wv][ln] = h0a + agg;
  }
  __syncthreads();

  {
    float acc = 0.f;
    #pragma unroll
    for (int k = 0; k < kDim; k += 4) {
      const float4 wk = *reinterpret_cast<const float4*>(wrow + k);
      const float4 pk = *reinterpret_cast<const float4*>(&s_pre0[wv][k]);
      acc = fmaf(wk.x, pk.x, acc);
      acc = fmaf(wk.y, pk.y, acc);
      acc = fmaf(wk.z, pk.z, acc);
      acc = fmaf(wk.w, pk.w, acc);
    }
    const float item = fast_tanh(acc + bln);  // final iter -> tanh
    float t = ue * item;
    #pragma unroll
    for (int off = 32; off > 0; off >>= 1)
      t += __shfl_xor(t, off, 64);
    if (ln == 0) out[b] = fast_sigmoid(t);
  }
}

}  // namespace

extern "C" void kernel_launch(void* const* d_in, const int* in_sizes, int n_in,
                              void* d_out, int out_size, void* d_ws, size_t ws_size,
                              hipStream_t stream) {
  const int*   u        = (const int*)d_in[0];
  const int*   v        = (const int*)d_in[1];
  const float* usr_emb  = (const float*)d_in[2];
  const float* item_emb = (const float*)d_in[3];
  const float* ent_emb  = (const float*)d_in[4];
  const float* rel_emb  = (const float*)d_in[5];
  const float* W        = (const float*)d_in[6];
  const float* bias     = (const float*)d_in[7];
  const int*   adj_ent  = (const int*)d_in[8];
  const int*   adj_rel  = (const int*)d_in[9];
  float*       out      = (float*)d_out;

  const int B = in_sizes[0];          // 16384, divisible by kElems
  dim3 grid(B / kElems), block(kElems * 64);
  hipLaunchKernelGGL(kgcn_kernel, grid, block, 0, stream,
                     u, v, usr_emb, item_emb, ent_emb, rel_emb, W, bias,
                     adj_ent, adj_rel, out);
}

// Round 2
// 123.000 us; speedup vs baseline: 1.4440x; 1.4440x over previous
//
#include <hip/hip_runtime.h>

// KGCN forward, MI355X. One wave per batch element for gather/attention
// (lane = dim); block-cooperative scalar-W GEMM phase for the 9 batchable
// matvecs (lane = pre-vector row, W via SGPR s_loads -> no L1 fan-out).

namespace {

constexpr int kDim      = 64;
constexpr int kNN       = 8;
constexpr int kNumEnt   = 100000;
constexpr int kItemInKG = 20000;
constexpr int kElems    = 4;              // batch elements (waves) per block
constexpr int kVecs     = 9;              // pre0 + 8x pre1 per element
constexpr int kRows     = kElems * kVecs; // 36 batched matvec rows per block
constexpr int kRowPad   = 68;             // floats/row: 272B = 16B-aligned, bank-spread

__device__ __forceinline__ float fast_sigmoid(float x) {
  return 1.0f / (1.0f + __expf(-x));
}
__device__ __forceinline__ float fast_tanh(float x) {
  return 2.0f / (1.0f + __expf(-2.0f * x)) - 1.0f;
}

__global__ void __launch_bounds__(kElems * 64)
kgcn_kernel(const int* __restrict__ u, const int* __restrict__ v,
            const float* __restrict__ usr_emb, const float* __restrict__ item_emb,
            const float* __restrict__ ent_emb, const float* __restrict__ rel_emb,
            const float* __restrict__ W, const float* __restrict__ bias,
            const int* __restrict__ adj_ent, const int* __restrict__ adj_rel,
            float* __restrict__ out)
{
  const int wv = threadIdx.x >> 6;   // wave within block = element slot
  const int ln = threadIdx.x & 63;   // lane
  const int b  = blockIdx.x * kElems + wv;

  __shared__ int s_e1[kElems][kNN];
  __shared__ int s_r1[kElems][kNN];
  __shared__ int s_e2[kElems][kDim];
  __shared__ int s_r2[kElems][kDim];
  // rows flattened: row r = e*9 + m; m==0 -> hop-0 vec, m==1+n -> hop-1 vec n
  __shared__ __align__(16) float s_pre[kRows][kRowPad];
  __shared__ __align__(16) float s_h[kRows][kRowPad];

  const int   uid = u[b];
  const int   vid = v[b];
  const float ue  = usr_emb[uid * kDim + ln];
  const float ev0 = item_emb[vid * kDim + ln];
  const int   e0  = (vid >= kItemInKG) ? kNumEnt : vid;   // pad entity for non-KG items

  if (ln < kNN) {
    s_e1[wv][ln] = adj_ent[e0 * kNN + ln];
    s_r1[wv][ln] = adj_rel[e0 * kNN + ln];
  }
  __syncthreads();

  // hop-2 adjacency: lane j -> neighbor (j&7) of hop-1 entity (j>>3)
  {
    const int parent = s_e1[wv][ln >> 3];
    s_e2[wv][ln] = adj_ent[parent * kNN + (ln & 7)];
    s_r2[wv][ln] = adj_rel[parent * kNN + (ln & 7)];
  }

  // hop-1 entity embeddings (lane = dim): registers only
  float ev1r[kNN];
  #pragma unroll
  for (int m = 0; m < kNN; ++m)
    ev1r[m] = ent_emb[s_e1[wv][m] * kDim + ln];

  // hop-0 attention weights (reused verbatim for iter-1 hop-0: same ue, same rv[0])
  float w0[kNN];
  {
    float p[kNN];
    #pragma unroll
    for (int n = 0; n < kNN; ++n)
      p[n] = ue * rel_emb[s_r1[wv][n] * kDim + ln];
    #pragma unroll
    for (int off = 32; off > 0; off >>= 1) {
      #pragma unroll
      for (int n = 0; n < kNN; ++n)
        p[n] += __shfl_xor(p[n], off, 64);
    }
    float mx = p[0];
    #pragma unroll
    for (int n = 1; n < kNN; ++n) mx = fmaxf(mx, p[n]);
    float sum = 0.f;
    #pragma unroll
    for (int n = 0; n < kNN; ++n) { w0[n] = __expf(p[n] - mx); sum += w0[n]; }
    const float inv = 1.f / sum;
    #pragma unroll
    for (int n = 0; n < kNN; ++n) w0[n] *= inv;
  }

  // iter-0 hop-0 pre-activation -> row wv*9 + 0
  {
    float agg = 0.f;
    #pragma unroll
    for (int n = 0; n < kNN; ++n) agg = fmaf(w0[n], ev1r[n], agg);
    s_pre[wv * kVecs + 0][ln] = ev0 + agg;
  }
  __syncthreads();   // s_e2/s_r2 visible

  // iter-0 hop-1 attention: rows wv*9 + 1+m
  #pragma unroll 1
  for (int m = 0; m < kNN; ++m) {
    float p[kNN];
    #pragma unroll
    for (int n = 0; n < kNN; ++n)
      p[n] = ue * rel_emb[s_r2[wv][m * kNN + n] * kDim + ln];
    #pragma unroll
    for (int off = 32; off > 0; off >>= 1) {
      #pragma unroll
      for (int n = 0; n < kNN; ++n)
        p[n] += __shfl_xor(p[n], off, 64);
    }
    float mx = p[0];
    #pragma unroll
    for (int n = 1; n < kNN; ++n) mx = fmaxf(mx, p[n]);
    float sum = 0.f;
    #pragma unroll
    for (int n = 0; n < kNN; ++n) { p[n] = __expf(p[n] - mx); sum += p[n]; }
    const float inv = 1.f / sum;   // softmax linear in agg: scale once
    float agg = 0.f;
    #pragma unroll
    for (int n = 0; n < kNN; ++n)
      agg = fmaf(p[n], ent_emb[s_e2[wv][m * kNN + n] * kDim + ln], agg);
    s_pre[wv * kVecs + 1 + m][ln] = fmaf(agg, inv, ev1r[m]);
  }
  __syncthreads();   // all 36 pre rows complete

  // ---- batched matvec: h[r][d] = sigmoid( sum_k pre[r][k] * W[d][k] + b[d] )
  // lane = row r (36 active); this wave handles d in [wv*16, wv*16+16).
  // W/bias indices are wave-uniform (readfirstlane) -> scalar s_loads.
  {
    const int dbase = __builtin_amdgcn_readfirstlane(wv << 4);
    if (ln < kRows) {
      const float* prow = &s_pre[ln][0];
      float acc[16];
      #pragma unroll
      for (int dd = 0; dd < 16; ++dd) acc[dd] = 0.f;

      #pragma unroll
      for (int h = 0; h < 2; ++h) {          // two k-halves: bound VGPRs
        float pr[32];
        #pragma unroll
        for (int c = 0; c < 8; ++c)
          *reinterpret_cast<float4*>(&pr[c * 4]) =
              *reinterpret_cast<const float4*>(prow + h * 32 + c * 4);
        #pragma unroll
        for (int dd = 0; dd < 16; ++dd) {
          const float* wr = W + (dbase + dd) * kDim + h * 32;  // uniform -> SGPR
          float a = acc[dd];
          #pragma unroll
          for (int k = 0; k < 32; ++k) a = fmaf(wr[k], pr[k], a);
          acc[dd] = a;
        }
      }
      float hv[16];
      #pragma unroll
      for (int dd = 0; dd < 16; ++dd)
        hv[dd] = fast_sigmoid(acc[dd] + bias[dbase + dd]);   // iter 0 -> sigmoid
      float* hrow = &s_h[ln][dbase];
      #pragma unroll
      for (int c = 0; c < 4; ++c)
        *reinterpret_cast<float4*>(hrow + c * 4) =
            make_float4(hv[c * 4], hv[c * 4 + 1], hv[c * 4 + 2], hv[c * 4 + 3]);
    }
  }
  __syncthreads();   // all h rows complete

  // iter-1 hop-0: reuse w0; neighbors are the hop-1 activations. lane = dim.
  {
    const float h0a = s_h[wv * kVecs + 0][ln];
    float agg = 0.f;
    #pragma unroll
    for (int n = 0; n < kNN; ++n)
      agg = fmaf(w0[n], s_h[wv * kVecs + 1 + n][ln], agg);
    s_pre[wv * kVecs + 0][ln] = h0a + agg;   // reuse row as staging
  }
  __syncthreads();

  // final matvec (1 vector/element): lane = output dim, W rows via L1 float4
  {
    const float* __restrict__ wrow = W + ln * kDim;
    const float* prow = &s_pre[wv * kVecs + 0][0];   // wave-uniform -> broadcast reads
    float acc = 0.f;
    #pragma unroll
    for (int k = 0; k < kDim; k += 4) {
      const float4 wk = *reinterpret_cast<const float4*>(wrow + k);
      const float4 pk = *reinterpret_cast<const float4*>(prow + k);
      acc = fmaf(wk.x, pk.x, acc);
      acc = fmaf(wk.y, pk.y, acc);
      acc = fmaf(wk.z, pk.z, acc);
      acc = fmaf(wk.w, pk.w, acc);
    }
    const float item = fast_tanh(acc + bias[ln]);    // final iter -> tanh
    float t = ue * item;
    #pragma unroll
    for (int off = 32; off > 0; off >>= 1)
      t += __shfl_xor(t, off, 64);
    if (ln == 0) out[b] = fast_sigmoid(t);
  }
}

}  // namespace

extern "C" void kernel_launch(void* const* d_in, const int* in_sizes, int n_in,
                              void* d_out, int out_size, void* d_ws, size_t ws_size,
                              hipStream_t stream) {
  const int*   u        = (const int*)d_in[0];
  const int*   v        = (const int*)d_in[1];
  const float* usr_emb  = (const float*)d_in[2];
  const float* item_emb = (const float*)d_in[3];
  const float* ent_emb  = (const float*)d_in[4];
  const float* rel_emb  = (const float*)d_in[5];
  const float* W        = (const float*)d_in[6];
  const float* bias     = (const float*)d_in[7];
  const int*   adj_ent  = (const int*)d_in[8];
  const int*   adj_rel  = (const int*)d_in[9];
  float*       out      = (float*)d_out;

  const int B = in_sizes[0];   // 16384, divisible by kElems
  dim3 grid(B / kElems), block(kElems * 64);
  hipLaunchKernelGGL(kgcn_kernel, grid, block, 0, stream,
                     u, v, usr_emb, item_emb, ent_emb, rel_emb, W, bias,
                     adj_ent, adj_rel, out);
}

// Round 3
// 90.926 us; speedup vs baseline: 1.9534x; 1.3527x over previous
//
#include <hip/hip_runtime.h>

// KGCN forward, MI355X. One wave per batch element, no __syncthreads (all LDS
// traffic is wave-internal; lgkmcnt ordering suffices).
// Phase layouts:
//   gather/agg/GEMM: lane = dim d
//   scores:          lane = (m,n) neighbor pair -> softmax needs only
//                    shfl_xor {1,2,4} within 8-lane groups
// W row d lives in 64 VGPRs per thread; loaded once, used by 10 matvecs.

namespace {

constexpr int kDim      = 64;
constexpr int kNN       = 8;
constexpr int kNumEnt   = 100000;
constexpr int kItemInKG = 20000;
constexpr int kElems    = 4;    // batch elements (waves) per block
constexpr int kVecs     = 9;    // pre0 + 8x pre1 rows per element
constexpr int kRowPad   = 68;   // 272B row stride: 16B-aligned

__device__ __forceinline__ float fast_sigmoid(float x) {
  return 1.0f / (1.0f + __expf(-x));
}
__device__ __forceinline__ float fast_tanh(float x) {
  return 2.0f / (1.0f + __expf(-2.0f * x)) - 1.0f;
}

__global__ void __launch_bounds__(kElems * 64)
kgcn_kernel(const int* __restrict__ u, const int* __restrict__ v,
            const float* __restrict__ usr_emb, const float* __restrict__ item_emb,
            const float* __restrict__ ent_emb, const float* __restrict__ rel_emb,
            const float* __restrict__ W, const float* __restrict__ bias,
            const int* __restrict__ adj_ent, const int* __restrict__ adj_rel,
            float* __restrict__ out)
{
  const int wv = threadIdx.x >> 6;
  const int ln = threadIdx.x & 63;
  const int b  = blockIdx.x * kElems + wv;

  __shared__ __align__(16) float s_ue[kElems][kDim];
  __shared__ int   s_e1[kElems][kNN];
  __shared__ int   s_e2[kElems][kDim];
  __shared__ float s_w2[kElems][kDim];
  __shared__ __align__(16) float s_pre[kElems][kVecs][kRowPad];

  const int   uid = u[b];
  const int   vid = v[b];
  const float ue  = usr_emb[uid * kDim + ln];
  s_ue[wv][ln] = ue;
  const float ev0 = item_emb[vid * kDim + ln];
  const int   e0  = (vid >= kItemInKG) ? kNumEnt : vid;  // pad entity for non-KG items

  // hop-1 adjacency (8 ids) -> LDS; r1 stays in the owning lane's register.
  int r1 = 0;
  if (ln < kNN) {
    s_e1[wv][ln] = adj_ent[e0 * kNN + ln];
    r1           = adj_rel[e0 * kNN + ln];
  }

  // hop-2 adjacency: lane = pair (m = ln>>3, n = ln&7). r2 register-resident.
  const int parent = s_e1[wv][ln >> 3];
  const int e2     = adj_ent[parent * kNN + (ln & 7)];
  const int r2     = adj_rel[parent * kNN + (ln & 7)];
  s_e2[wv][ln] = e2;

  // hop-1 entity embeddings (lane = dim), register-resident.
  float ev1r[kNN];
  #pragma unroll
  for (int m = 0; m < kNN; ++m)
    ev1r[m] = ent_emb[(size_t)s_e1[wv][m] * kDim + ln];

  // ---- scores, lane = pair: s2 = dot(ue, rel_emb[r2]). rel table 15.6KB -> L1.
  float s2 = 0.f;
  {
    const float* rr = rel_emb + (size_t)r2 * kDim;
    #pragma unroll
    for (int k4 = 0; k4 < 16; ++k4) {
      const float4 r = *reinterpret_cast<const float4*>(rr + k4 * 4);
      const float4 q = *reinterpret_cast<const float4*>(&s_ue[wv][k4 * 4]);
      s2 = fmaf(r.x, q.x, s2);
      s2 = fmaf(r.y, q.y, s2);
      s2 = fmaf(r.z, q.z, s2);
      s2 = fmaf(r.w, q.w, s2);
    }
  }
  // softmax within each 8-lane n-group: masks 1,2,4 stay inside the group.
  {
    float mx = s2;
    #pragma unroll
    for (int msk = 1; msk <= 4; msk <<= 1)
      mx = fmaxf(mx, __shfl_xor(mx, msk, 64));
    float w = __expf(s2 - mx);
    float sm = w;
    #pragma unroll
    for (int msk = 1; msk <= 4; msk <<= 1)
      sm += __shfl_xor(sm, msk, 64);
    s_w2[wv][ln] = w / sm;
  }

  // hop-0 scores on lanes 0..7 (sources of every shfl are active lanes 0..7).
  float w0v = 0.f;
  if (ln < kNN) {
    const float* rr = rel_emb + (size_t)r1 * kDim;
    float s0 = 0.f;
    #pragma unroll
    for (int k4 = 0; k4 < 16; ++k4) {
      const float4 r = *reinterpret_cast<const float4*>(rr + k4 * 4);
      const float4 q = *reinterpret_cast<const float4*>(&s_ue[wv][k4 * 4]);
      s0 = fmaf(r.x, q.x, s0);
      s0 = fmaf(r.y, q.y, s0);
      s0 = fmaf(r.z, q.z, s0);
      s0 = fmaf(r.w, q.w, s0);
    }
    float mx = s0;
    #pragma unroll
    for (int msk = 1; msk <= 4; msk <<= 1)
      mx = fmaxf(mx, __shfl_xor(mx, msk, 64));
    w0v = __expf(s0 - mx);
    float sm = w0v;
    #pragma unroll
    for (int msk = 1; msk <= 4; msk <<= 1)
      sm += __shfl_xor(sm, msk, 64);
    w0v /= sm;
  }

  // ---- aggregation, lane = dim ----
  // hop-0 pre (row 0): item_emb[v] + sum_n w0[n]*ent_emb[e1[n]]
  {
    float agg = 0.f;
    #pragma unroll
    for (int n = 0; n < kNN; ++n)
      agg = fmaf(__shfl(w0v, n, 64), ev1r[n], agg);
    s_pre[wv][0][ln] = ev0 + agg;
  }
  // hop-1 pre (rows 1..8): ent gathers are the main L2 traffic.
  #pragma unroll 2
  for (int m = 0; m < kNN; ++m) {
    float agg = 0.f;
    #pragma unroll
    for (int n = 0; n < kNN; ++n) {
      const int idx = m * kNN + n;
      agg = fmaf(s_w2[wv][idx],
                 ent_emb[(size_t)s_e2[wv][idx] * kDim + ln], agg);
    }
    s_pre[wv][1 + m][ln] = ev1r[m] + agg;
  }

  // ---- W row d -> 64 VGPRs (once), then 9 batched matvecs + 1 final ----
  const float bln = bias[ln];
  const float* __restrict__ wrow = W + ln * kDim;
  float4 Wreg[16];
  #pragma unroll
  for (int k4 = 0; k4 < 16; ++k4)
    Wreg[k4] = *reinterpret_cast<const float4*>(wrow + k4 * 4);

  float h[kVecs];
  #pragma unroll
  for (int m = 0; m < kVecs; ++m) {
    float acc = 0.f;
    #pragma unroll
    for (int k4 = 0; k4 < 16; ++k4) {
      const float4 p = *reinterpret_cast<const float4*>(&s_pre[wv][m][k4 * 4]);
      acc = fmaf(Wreg[k4].x, p.x, acc);
      acc = fmaf(Wreg[k4].y, p.y, acc);
      acc = fmaf(Wreg[k4].z, p.z, acc);
      acc = fmaf(Wreg[k4].w, p.w, acc);
    }
    h[m] = fast_sigmoid(acc + bln);   // iter 0 -> sigmoid
  }

  // iter-1 hop-0: same attention weights (same ue, same rv[0]) -> reuse w0.
  {
    float pre = h[0];
    #pragma unroll
    for (int n = 0; n < kNN; ++n)
      pre = fmaf(__shfl(w0v, n, 64), h[1 + n], pre);
    s_pre[wv][0][ln] = pre;           // stage for broadcast reads
  }

  {
    float acc = 0.f;
    #pragma unroll
    for (int k4 = 0; k4 < 16; ++k4) {
      const float4 p = *reinterpret_cast<const float4*>(&s_pre[wv][0][k4 * 4]);
      acc = fmaf(Wreg[k4].x, p.x, acc);
      acc = fmaf(Wreg[k4].y, p.y, acc);
      acc = fmaf(Wreg[k4].z, p.z, acc);
      acc = fmaf(Wreg[k4].w, p.w, acc);
    }
    const float item = fast_tanh(acc + bln);   // final iter -> tanh
    float t = ue * item;
    #pragma unroll
    for (int off = 32; off > 0; off >>= 1)
      t += __shfl_xor(t, off, 64);
    if (ln == 0) out[b] = fast_sigmoid(t);
  }
}

}  // namespace

extern "C" void kernel_launch(void* const* d_in, const int* in_sizes, int n_in,
                              void* d_out, int out_size, void* d_ws, size_t ws_size,
                              hipStream_t stream) {
  const int*   u        = (const int*)d_in[0];
  const int*   v        = (const int*)d_in[1];
  const float* usr_emb  = (const float*)d_in[2];
  const float* item_emb = (const float*)d_in[3];
  const float* ent_emb  = (const float*)d_in[4];
  const float* rel_emb  = (const float*)d_in[5];
  const float* W        = (const float*)d_in[6];
  const float* bias     = (const float*)d_in[7];
  const int*   adj_ent  = (const int*)d_in[8];
  const int*   adj_rel  = (const int*)d_in[9];
  float*       out      = (float*)d_out;

  const int B = in_sizes[0];   // 16384, divisible by kElems
  dim3 grid(B / kElems), block(kElems * 64);
  hipLaunchKernelGGL(kgcn_kernel, grid, block, 0, stream,
                     u, v, usr_emb, item_emb, ent_emb, rel_emb, W, bias,
                     adj_ent, adj_rel, out);
}

// Round 4
// 64.549 us; speedup vs baseline: 2.7516x; 1.4086x over previous
//
#include <hip/hip_runtime.h>

// KGCN forward, MI355X. 8 waves/block (512 thr), one wave per batch element.
// Key structure:
//  - W (16KB) staged to LDS once per block, XOR-chunk-swizzled so the
//    per-lane row reads (ds_read_b128) are conflict-free; cached in 64 VGPRs.
//  - rel_emb staged TRANSPOSED (stride 65) -> t[r] = ue.rel[r] computed for
//    all 61 relations in one contiguous-LDS pass (lane = r); every attention
//    score is then a single LDS lookup t[r]. No fan-out global loads remain.
//  - All 72 ent_emb gathers issued before the score phase (deep MLP),
//    addresses via readfirstlane (SALU) since entity ids are wave-uniform.

namespace {

constexpr int kDim      = 64;
constexpr int kNN       = 8;
constexpr int kNumEnt   = 100000;
constexpr int kItemInKG = 20000;
constexpr int kElems    = 8;    // batch elements (waves) per block
constexpr int kVecs     = 9;    // pre0 + 8x pre1 rows per element
constexpr int kRelChunks = 976; // 61 rel rows * 16 float4 chunks

__device__ __forceinline__ float fast_sigmoid(float x) {
  return 1.0f / (1.0f + __expf(-x));
}
__device__ __forceinline__ float fast_tanh(float x) {
  return 2.0f / (1.0f + __expf(-2.0f * x)) - 1.0f;
}

__global__ void __launch_bounds__(kElems * 64)
kgcn_kernel(const int* __restrict__ u, const int* __restrict__ v,
            const float* __restrict__ usr_emb, const float* __restrict__ item_emb,
            const float* __restrict__ ent_emb, const float* __restrict__ rel_emb,
            const float* __restrict__ W, const float* __restrict__ bias,
            const int* __restrict__ adj_ent, const int* __restrict__ adj_rel,
            float* __restrict__ out)
{
  const int tid = threadIdx.x;
  const int wv  = tid >> 6;
  const int ln  = tid & 63;
  const int b   = blockIdx.x * kElems + wv;

  __shared__ float4 s_w4[kDim * 16];        // W chunks, col ^= (row&7) swizzle
  __shared__ float  s_relt[kDim * 65];      // rel^T: [k][r], row stride 65
  __shared__ float  s_t[kElems][kDim];      // t[r] = ue . rel_emb[r]
  __shared__ int    s_e1[kElems][kNN];
  __shared__ int    s_e2[kElems][kDim];
  __shared__ float  s_w2[kElems][kDim];
  __shared__ float  s_ue[kElems][kDim];
  __shared__ __align__(16) float s_pre[kElems][kVecs][kDim];

  // ---- A: issue cooperative staging loads (coalesced float4) ----
  const float4* W4 = reinterpret_cast<const float4*>(W);
  const float4* R4 = reinterpret_cast<const float4*>(rel_emb);
  float4 wst[2], rst[2];
  #pragma unroll
  for (int i = 0; i < 2; ++i) wst[i] = W4[i * 512 + tid];
  #pragma unroll
  for (int i = 0; i < 2; ++i) {
    const int id = i * 512 + tid;
    rst[i] = (id < kRelChunks) ? R4[id] : make_float4(0.f, 0.f, 0.f, 0.f);
  }

  // ---- B: adjacency dependency chain (3 levels, unavoidable) ----
  const int   uid = u[b];
  const int   vid = v[b];
  const float ue  = usr_emb[(size_t)uid * kDim + ln];
  s_ue[wv][ln] = ue;
  const float ev0 = item_emb[(size_t)vid * kDim + ln];
  const int   e0  = (vid >= kItemInKG) ? kNumEnt : vid;  // pad entity outside KG

  int r1 = 0;
  if (ln < kNN) {
    s_e1[wv][ln] = adj_ent[(size_t)e0 * kNN + ln];
    r1           = adj_rel[(size_t)e0 * kNN + ln];
  }
  const int parent = s_e1[wv][ln >> 3];          // wave-local LDS round trip
  const int e2     = adj_ent[(size_t)parent * kNN + (ln & 7)];
  const int r2     = adj_rel[(size_t)parent * kNN + (ln & 7)];
  s_e2[wv][ln] = e2;

  // ---- A2: staging writes (banks analyzed <=2-way everywhere) ----
  #pragma unroll
  for (int i = 0; i < 2; ++i) {
    const int id  = i * 512 + tid;
    const int row = id >> 4, col = id & 15;
    s_w4[(row << 4) | (col & 8) | ((col ^ row) & 7)] = wst[i];
  }
  #pragma unroll
  for (int i = 0; i < 2; ++i) {
    const int id = i * 512 + tid;
    if (id < kRelChunks) {
      const int r = id >> 4, c = (id & 15) << 2;
      s_relt[(c + 0) * 65 + r] = rst[i].x;
      s_relt[(c + 1) * 65 + r] = rst[i].y;
      s_relt[(c + 2) * 65 + r] = rst[i].z;
      s_relt[(c + 3) * 65 + r] = rst[i].w;
    }
  }

  // ---- C/D: issue ALL ent_emb gathers now (72 loads in flight over the
  // score phase). Entity ids are wave-uniform -> readfirstlane -> SALU addr.
  float ev1r[kNN];
  #pragma unroll
  for (int m = 0; m < kNN; ++m) {
    const int e1u = __builtin_amdgcn_readfirstlane(s_e1[wv][m]);
    ev1r[m] = ent_emb[(size_t)e1u * kDim + ln];
  }
  float g[kDim];
  #pragma unroll
  for (int i = 0; i < kDim; ++i) {
    const int e2u = __builtin_amdgcn_readfirstlane(s_e2[wv][i]);
    g[i] = ent_emb[(size_t)e2u * kDim + ln];
  }

  __syncthreads();   // staging (s_w4, s_relt) visible; gathers stay in flight

  // ---- F: t[r] = dot(ue, rel_emb[r]) for all relations, lane = r.
  // s_relt row k is contiguous across lanes -> conflict-free; ue[k] broadcast.
  {
    float a0 = 0.f, a1 = 0.f, a2 = 0.f, a3 = 0.f;
    #pragma unroll
    for (int k = 0; k < kDim; k += 4) {
      a0 = fmaf(s_ue[wv][k + 0], s_relt[(k + 0) * 65 + ln], a0);
      a1 = fmaf(s_ue[wv][k + 1], s_relt[(k + 1) * 65 + ln], a1);
      a2 = fmaf(s_ue[wv][k + 2], s_relt[(k + 2) * 65 + ln], a2);
      a3 = fmaf(s_ue[wv][k + 3], s_relt[(k + 3) * 65 + ln], a3);
    }
    s_t[wv][ln] = (a0 + a1) + (a2 + a3);   // lanes 61..63 hold junk, never read
  }

  // ---- G: softmaxes from score lookups. 8-lane groups, masks {1,2,4}.
  {
    const float s2 = s_t[wv][r2];
    float mx = s2;
    #pragma unroll
    for (int m = 1; m <= 4; m <<= 1) mx = fmaxf(mx, __shfl_xor(mx, m, 64));
    const float e = __expf(s2 - mx);
    float sm = e;
    #pragma unroll
    for (int m = 1; m <= 4; m <<= 1) sm += __shfl_xor(sm, m, 64);
    s_w2[wv][ln] = e / sm;
  }
  float w0v = 0.f;
  if (ln < kNN) {
    const float s0 = s_t[wv][r1];
    float mx = s0;
    #pragma unroll
    for (int m = 1; m <= 4; m <<= 1) mx = fmaxf(mx, __shfl_xor(mx, m, 64));
    w0v = __expf(s0 - mx);
    float sm = w0v;
    #pragma unroll
    for (int m = 1; m <= 4; m <<= 1) sm += __shfl_xor(sm, m, 64);
    w0v /= sm;
  }

  // ---- H: aggregation (lane = dim), consuming the in-flight gathers ----
  {
    float agg = 0.f;
    #pragma unroll
    for (int n = 0; n < kNN; ++n)
      agg = fmaf(__shfl(w0v, n, 64), ev1r[n], agg);
    s_pre[wv][0][ln] = ev0 + agg;
  }
  #pragma unroll
  for (int m = 0; m < kNN; ++m) {
    float acc = 0.f;
    #pragma unroll
    for (int n = 0; n < kNN; ++n)
      acc = fmaf(s_w2[wv][m * kNN + n], g[m * kNN + n], acc);
    s_pre[wv][1 + m][ln] = ev1r[m] + acc;
  }

  // ---- I: W row ln -> 64 VGPRs via swizzled conflict-free LDS reads.
  // Stored chunk (c ^ (row&7)) read at (k4 ^ (ln&7)) returns natural-order
  // content: Wreg[k4] = W[ln][4*k4 .. 4*k4+3].
  float4 Wreg[16];
  #pragma unroll
  for (int k4 = 0; k4 < 16; ++k4)
    Wreg[k4] = s_w4[(ln << 4) | (k4 & 8) | ((k4 ^ ln) & 7)];

  const float bln = bias[ln];

  // ---- J: 9 batched matvecs (p-reads are wave-uniform broadcasts) ----
  float h[kVecs];
  #pragma unroll
  for (int m = 0; m < kVecs; ++m) {
    float acc = 0.f;
    #pragma unroll
    for (int k4 = 0; k4 < 16; ++k4) {
      const float4 p = *reinterpret_cast<const float4*>(&s_pre[wv][m][k4 * 4]);
      acc = fmaf(Wreg[k4].x, p.x, acc);
      acc = fmaf(Wreg[k4].y, p.y, acc);
      acc = fmaf(Wreg[k4].z, p.z, acc);
      acc = fmaf(Wreg[k4].w, p.w, acc);
    }
    h[m] = fast_sigmoid(acc + bln);   // iter 0 -> sigmoid
  }

  // ---- K: iter-1 hop-0 (same ue, same rels -> reuse w0) ----
  {
    float pre = h[0];
    #pragma unroll
    for (int n = 0; n < kNN; ++n)
      pre = fmaf(__shfl(w0v, n, 64), h[1 + n], pre);
    s_pre[wv][0][ln] = pre;
  }

  // ---- L: final matvec + tanh + user dot ----
  {
    float acc = 0.f;
    #pragma unroll
    for (int k4 = 0; k4 < 16; ++k4) {
      const float4 p = *reinterpret_cast<const float4*>(&s_pre[wv][0][k4 * 4]);
      acc = fmaf(Wreg[k4].x, p.x, acc);
      acc = fmaf(Wreg[k4].y, p.y, acc);
      acc = fmaf(Wreg[k4].z, p.z, acc);
      acc = fmaf(Wreg[k4].w, p.w, acc);
    }
    const float item = fast_tanh(acc + bln);
    float t = ue * item;
    #pragma unroll
    for (int off = 32; off > 0; off >>= 1)
      t += __shfl_xor(t, off, 64);
    if (ln == 0) out[b] = fast_sigmoid(t);
  }
}

}  // namespace

extern "C" void kernel_launch(void* const* d_in, const int* in_sizes, int n_in,
                              void* d_out, int out_size, void* d_ws, size_t ws_size,
                              hipStream_t stream) {
  const int*   u        = (const int*)d_in[0];
  const int*   v        = (const int*)d_in[1];
  const float* usr_emb  = (const float*)d_in[2];
  const float* item_emb = (const float*)d_in[3];
  const float* ent_emb  = (const float*)d_in[4];
  const float* rel_emb  = (const float*)d_in[5];
  const float* W        = (const float*)d_in[6];
  const float* bias     = (const float*)d_in[7];
  const int*   adj_ent  = (const int*)d_in[8];
  const int*   adj_rel  = (const int*)d_in[9];
  float*       out      = (float*)d_out;

  const int B = in_sizes[0];   // 16384, divisible by kElems=8
  dim3 grid(B / kElems), block(kElems * 64);
  hipLaunchKernelGGL(kgcn_kernel, grid, block, 0, stream,
                     u, v, usr_emb, item_emb, ent_emb, rel_emb, W, bias,
                     adj_ent, adj_rel, out);
}